// Round 1
// baseline (11164.935 us; speedup 1.0000x reference)
//
#include <hip/hip_runtime.h>

#define D 4096
#define NH 32
#define NKV 8
#define HD 128
#define FF 14336
#define VOC 1024
#define TT 32
#define GENN 8
#define SEQ 9

// workspace offsets (floats)
#define OFF_BUF   0ull
#define OFF_HT    1179648ull
#define OFF_Q     1310720ull
#define OFF_KC    1441792ull
#define OFF_VC    1736704ull
#define OFF_AOT   2031616ull
#define OFF_XP    2162688ull
#define OFF_H2T   2293760ull
#define OFF_XOT   2424832ull
#define OFF_INT   2555904ull
#define OFF_PART  3014656ull

__global__ void k_init(const float* __restrict__ x0, float* __restrict__ buf) {
    int i = blockIdx.x * 256 + threadIdx.x;   // T*D threads
    int t = i / D, d = i % D;
    buf[(size_t)t * SEQ * D + d] = x0[i];
}

__global__ void k_rmsnorm(const float* __restrict__ base, int rowStride,
                          const float* __restrict__ w, float* __restrict__ outT) {
    int t = blockIdx.x;
    const float* x = base + (size_t)t * rowStride;
    float ss = 0.f;
    for (int d = threadIdx.x; d < D; d += 256) { float v = x[d]; ss += v * v; }
    #pragma unroll
    for (int m = 1; m < 64; m <<= 1) ss += __shfl_xor(ss, m);
    __shared__ float red[4];
    int wid = threadIdx.x >> 6;
    if ((threadIdx.x & 63) == 0) red[wid] = ss;
    __syncthreads();
    float tot = red[0] + red[1] + red[2] + red[3];
    float r = 1.0f / sqrtf(tot / (float)D + 1e-5f);
    for (int d = threadIdx.x; d < D; d += 256)
        outT[(size_t)d * TT + t] = x[d] * r * w[d];
}

// Y_partial[split][n][m] = sum_{k in split} X[m][k] * W[n][k]
// XT is [K][32] (transposed activations). One wave per block; lane <-> column.
__global__ __launch_bounds__(64) void k_gemm(const float* __restrict__ XT,
        const float* __restrict__ W, float* __restrict__ part,
        int N, int K, int ntiles, int chunksPerSplit) {
    int tile  = blockIdx.x % ntiles;
    int split = blockIdx.x / ntiles;
    int lane = threadIdx.x;
    int n0 = tile * 64;
    int c0 = split * chunksPerSplit;
    __shared__ float4 wl[64 * 9];   // 64 rows x 32 floats, padded stride 36 floats
    float acc[32];
    #pragma unroll
    for (int m = 0; m < 32; ++m) acc[m] = 0.f;
    int rl = lane >> 3, kq = lane & 7;
    for (int c = 0; c < chunksPerSplit; ++c) {
        int k0 = (c0 + c) * 32;
        #pragma unroll
        for (int it = 0; it < 8; ++it) {
            int row = it * 8 + rl;
            const float4* src = (const float4*)(W + (size_t)(n0 + row) * K + k0 + kq * 4);
            wl[row * 9 + kq] = *src;
        }
        __syncthreads();
        const float* wrow = (const float*)wl + lane * 36;
        const float* xc = XT + (size_t)k0 * TT;
        #pragma unroll 4
        for (int kk = 0; kk < 32; ++kk) {
            float wv = wrow[kk];
            const float* xk = xc + kk * TT;
            #pragma unroll
            for (int m = 0; m < 32; ++m) acc[m] = fmaf(xk[m], wv, acc[m]);
        }
        __syncthreads();
    }
    float* dst = part + (size_t)split * N * TT + (size_t)(n0 + lane) * TT;
    #pragma unroll
    for (int m = 0; m < 32; ++m) dst[m] = acc[m];
}

// reduce q/k/v partials (8 splits), apply RoPE at position p, scatter into caches
__global__ void k_qkv_finish(const float* __restrict__ pQ, const float* __restrict__ pK,
                             const float* __restrict__ pV, float* __restrict__ q,
                             float* __restrict__ kc, float* __restrict__ vc, int p) {
    int idx = blockIdx.x * 256 + threadIdx.x;
    float fp = (float)p;
    if (idx < TT * NH * 64) {
        int d = idx & 63, h = (idx >> 6) & 31, t = idx >> 11;
        int n0 = h * HD + d, n1 = n0 + 64;
        float a = 0.f, b = 0.f;
        #pragma unroll
        for (int s = 0; s < 8; ++s) {
            a += pQ[(size_t)s * D * TT + (size_t)n0 * TT + t];
            b += pQ[(size_t)s * D * TT + (size_t)n1 * TT + t];
        }
        float ang = fp * powf(500000.0f, -(float)d * (1.0f / 64.0f));
        float cs = cosf(ang), sn = sinf(ang);
        q[(size_t)t * D + n0] = a * cs - b * sn;
        q[(size_t)t * D + n1] = b * cs + a * sn;
    } else if (idx < TT * NH * 64 + TT * NKV * 64) {
        int r = idx - TT * NH * 64;
        int d = r & 63, kvh = (r >> 6) & 7, t = r >> 9;
        int n0 = kvh * HD + d, n1 = n0 + 64;
        float a = 0.f, b = 0.f;
        #pragma unroll
        for (int s = 0; s < 8; ++s) {
            a += pK[(size_t)s * 1024 * TT + (size_t)n0 * TT + t];
            b += pK[(size_t)s * 1024 * TT + (size_t)n1 * TT + t];
        }
        float ang = fp * powf(500000.0f, -(float)d * (1.0f / 64.0f));
        float cs = cosf(ang), sn = sinf(ang);
        float* krow = kc + (((size_t)t * SEQ + p) * NKV + kvh) * HD;
        krow[d] = a * cs - b * sn;
        krow[d + 64] = b * cs + a * sn;
    } else {
        int r = idx - (TT * NH * 64 + TT * NKV * 64);
        int d = r & 127, kvh = (r >> 7) & 7, t = r >> 10;
        float a = 0.f;
        #pragma unroll
        for (int s = 0; s < 8; ++s)
            a += pV[(size_t)s * 1024 * TT + (size_t)(kvh * HD + d) * TT + t];
        vc[(((size_t)t * SEQ + p) * NKV + kvh) * HD + d] = a;
    }
}

__global__ __launch_bounds__(64) void k_attn(const float* __restrict__ q,
        const float* __restrict__ kc, const float* __restrict__ vc,
        float* __restrict__ aoT, int p) {
    int t = blockIdx.x >> 5;
    int h = blockIdx.x & 31;
    int kvh = h >> 2;                // G = NH/NKV = 4
    int lane = threadIdx.x;
    const float* qp = q + (size_t)t * D + h * HD;
    float q0 = qp[lane], q1 = qp[lane + 64];
    const float scale = 0.08838834764831845f;  // 1/sqrt(128)
    float s[SEQ];
    float mx = -1e30f;
    #pragma unroll
    for (int j = 0; j < SEQ; ++j) {
        const float* kr = kc + (((size_t)t * SEQ + j) * NKV + kvh) * HD;
        float ps = q0 * kr[lane] + q1 * kr[lane + 64];
        #pragma unroll
        for (int m = 1; m < 64; m <<= 1) ps += __shfl_xor(ps, m);
        ps = (j <= p) ? ps * scale : -1e30f;
        s[j] = ps;
        mx = fmaxf(mx, ps);
    }
    float denom = 0.f;
    #pragma unroll
    for (int j = 0; j < SEQ; ++j) {
        float e = expf(s[j] - mx);
        e = (j <= p) ? e : 0.f;
        s[j] = e; denom += e;
    }
    float inv = 1.0f / denom;
    float o0 = 0.f, o1 = 0.f;
    #pragma unroll
    for (int j = 0; j < SEQ; ++j) {
        const float* vr = vc + (((size_t)t * SEQ + j) * NKV + kvh) * HD;
        float w = s[j] * inv;
        o0 = fmaf(w, vr[lane], o0);
        o1 = fmaf(w, vr[lane + 64], o1);
    }
    aoT[(size_t)(h * HD + lane) * TT + t] = o0;
    aoT[(size_t)(h * HD + lane + 64) * TT + t] = o1;
}

__global__ void k_reduce_o(const float* __restrict__ part, const float* __restrict__ buf,
                           float* __restrict__ xp, int p) {
    int idx = blockIdx.x * 256 + threadIdx.x;   // D*32
    int n = idx >> 5, t = idx & 31;
    float a = 0.f;
    #pragma unroll
    for (int s = 0; s < 8; ++s) a += part[(size_t)s * D * TT + idx];
    xp[(size_t)t * D + n] = a + buf[((size_t)t * SEQ + p) * D + n];
}

__global__ void k_silu_mul(const float* __restrict__ pG, const float* __restrict__ pU,
                           float* __restrict__ outT) {
    int idx = blockIdx.x * 256 + threadIdx.x;   // FF*32
    float g = pG[idx] + pG[(size_t)FF * TT + idx];
    float u = pU[idx] + pU[(size_t)FF * TT + idx];
    float sg = g / (1.0f + expf(-g));
    outT[idx] = sg * u;
}

__global__ void k_reduce_d(const float* __restrict__ part, const float* __restrict__ xp,
                           float* __restrict__ xoT) {
    int idx = blockIdx.x * 256 + threadIdx.x;   // D*32
    int n = idx >> 5, t = idx & 31;
    float a = 0.f;
    #pragma unroll
    for (int s = 0; s < 8; ++s) a += part[(size_t)s * D * TT + idx];
    xoT[idx] = a + xp[(size_t)t * D + n];
}

__global__ void k_head(const float* __restrict__ part, const float* __restrict__ bias,
                       const float* __restrict__ emb, int* __restrict__ toks,
                       float* __restrict__ buf, int p) {
    int t = blockIdx.x;
    int tid = threadIdx.x;
    float bv = -1e30f; int bi = 0;
    for (int n = tid; n < VOC; n += 256) {
        float a = bias[n];
        #pragma unroll
        for (int s = 0; s < 8; ++s) a += part[(size_t)s * VOC * TT + (size_t)n * TT + t];
        if (a > bv) { bv = a; bi = n; }   // ascending n -> first max kept
    }
    __shared__ float sv[256];
    __shared__ int si[256];
    sv[tid] = bv; si[tid] = bi;
    __syncthreads();
    for (int off = 128; off > 0; off >>= 1) {
        if (tid < off) {
            float v2 = sv[tid + off]; int i2 = si[tid + off];
            if (v2 > sv[tid] || (v2 == sv[tid] && i2 < si[tid])) { sv[tid] = v2; si[tid] = i2; }
        }
        __syncthreads();
    }
    int tok = si[0];
    if (tid == 0) toks[t * GENN + p] = tok;
    const float* er = emb + (size_t)tok * D;
    float* brow = buf + ((size_t)t * SEQ + (p + 1)) * D;
    for (int d = tid; d < D; d += 256) brow[d] = er[d];
}

extern "C" void kernel_launch(void* const* d_in, const int* in_sizes, int n_in,
                              void* d_out, int out_size, void* d_ws, size_t ws_size,
                              hipStream_t stream) {
    const float* x0   = (const float*)d_in[0];
    const float* Wq   = (const float*)d_in[1];
    const float* Wk   = (const float*)d_in[2];
    const float* Wv   = (const float*)d_in[3];
    const float* Wo   = (const float*)d_in[4];
    const float* wln1 = (const float*)d_in[5];
    const float* wln2 = (const float*)d_in[6];
    const float* Wg   = (const float*)d_in[7];
    const float* Wu   = (const float*)d_in[8];
    const float* Wd   = (const float*)d_in[9];
    const float* emb  = (const float*)d_in[11];
    const float* Wout = (const float*)d_in[12];
    const float* bout = (const float*)d_in[13];

    float* ws   = (float*)d_ws;
    float* buf  = ws + OFF_BUF;
    float* hT   = ws + OFF_HT;
    float* qb   = ws + OFF_Q;
    float* kc   = ws + OFF_KC;
    float* vc   = ws + OFF_VC;
    float* aoT  = ws + OFF_AOT;
    float* xp   = ws + OFF_XP;
    float* h2T  = ws + OFF_H2T;
    float* xoT  = ws + OFF_XOT;
    float* intT = ws + OFF_INT;
    float* part = ws + OFF_PART;
    float* pQ = part;
    float* pK = part + 8ull * D * TT;
    float* pV = pK + 8ull * 1024 * TT;
    float* pG = part;
    float* pU = part + 2ull * FF * TT;

    k_init<<<512, 256, 0, stream>>>(x0, buf);
    for (int p = 0; p < GENN; ++p) {
        k_rmsnorm<<<32, 256, 0, stream>>>(buf + (size_t)p * D, SEQ * D, wln1, hT);
        k_gemm<<<64 * 8, 64, 0, stream>>>(hT, Wq, pQ, D, D, 64, 16);
        k_gemm<<<16 * 8, 64, 0, stream>>>(hT, Wk, pK, 1024, D, 16, 16);
        k_gemm<<<16 * 8, 64, 0, stream>>>(hT, Wv, pV, 1024, D, 16, 16);
        k_qkv_finish<<<448, 256, 0, stream>>>(pQ, pK, pV, qb, kc, vc, p);
        k_attn<<<1024, 64, 0, stream>>>(qb, kc, vc, aoT, p);
        k_gemm<<<64 * 8, 64, 0, stream>>>(aoT, Wo, part, D, D, 64, 16);
        k_reduce_o<<<512, 256, 0, stream>>>(part, buf, xp, p);
        k_rmsnorm<<<32, 256, 0, stream>>>(xp, D, wln2, h2T);
        k_gemm<<<224 * 2, 64, 0, stream>>>(h2T, Wg, pG, FF, D, 224, 64);
        k_gemm<<<224 * 2, 64, 0, stream>>>(h2T, Wu, pU, FF, D, 224, 64);
        k_silu_mul<<<1792, 256, 0, stream>>>(pG, pU, intT);
        k_gemm<<<64 * 8, 64, 0, stream>>>(intT, Wd, part, D, FF, 64, 56);
        k_reduce_d<<<512, 256, 0, stream>>>(part, xp, xoT);
        k_gemm<<<16 * 8, 64, 0, stream>>>(xoT, Wout, part, VOC, D, 16, 16);
        k_head<<<32, 256, 0, stream>>>(part, bout, emb, (int*)d_out, buf, p);
    }
}